// Round 5
// baseline (32914.148 us; speedup 1.0000x reference)
//
#include <hip/hip_runtime.h>
#include <hip/hip_fp16.h>

// B=64, T=512, D=96, H=256
constexpr int Tt = 512, Dd = 96, Hh = 256;
constexpr int NS0 = 16;   // h0 ring depth
constexpr int NSP = 8;    // P ring depth
typedef unsigned long long u64;

// ws byte offsets:
constexpr size_t OFF_P0  = (size_t)4 << 20;
constexpr size_t OFF_P1  = (size_t)12 << 20;
constexpr size_t OFF_FLG = (size_t)20 << 20;
constexpr size_t OFF_W16 = ((size_t)20 << 20) + ((size_t)64 << 10);
constexpr size_t oGW0 = 0;
constexpr size_t oGU0 = oGW0 + (size_t)48 * 768;
constexpr size_t oGW1 = oGU0 + (size_t)128 * 768;
constexpr size_t oGU1 = oGW1 + (size_t)128 * 768;
constexpr size_t oLW0 = oGU1 + (size_t)128 * 768;
constexpr size_t oLU0 = oLW0 + (size_t)48 * 1024;
constexpr size_t oLW1 = oLU0 + (size_t)128 * 1024;
constexpr size_t oLU1 = oLW1 + (size_t)128 * 1024;

__device__ __forceinline__ float sigf(float v) { return 1.0f / (1.0f + __expf(-v)); }
__device__ __forceinline__ u64 agld(const u64* p) {
    return __hip_atomic_load(p, __ATOMIC_RELAXED, __HIP_MEMORY_SCOPE_AGENT);
}
__device__ __forceinline__ int agldi(const int* p) {
    return __hip_atomic_load(p, __ATOMIC_ACQUIRE, __HIP_MEMORY_SCOPE_AGENT);
}
// tag+payload in ONE aligned 64-bit word -> relaxed agent-scope store is a
// sufficient (single-copy atomic) publish and it coalesces.
__device__ __forceinline__ void agst(u64* p, u64 v) {
    __hip_atomic_store(p, v, __ATOMIC_RELAXED, __HIP_MEMORY_SCOPE_AGENT);
}

// fp16x2 dot into f32 accumulator (v_dot2_f32_f16)
__device__ __forceinline__ float dot2f(unsigned w, unsigned a, float acc) {
#if __has_builtin(__builtin_amdgcn_fdot2)
    typedef _Float16 h2v __attribute__((ext_vector_type(2)));
    h2v wh, ah;
    __builtin_memcpy(&wh, &w, 4);
    __builtin_memcpy(&ah, &a, 4);
    return __builtin_amdgcn_fdot2(wh, ah, acc, false);
#else
    const float2 wf = __half22float2(*(const __half2*)&w);
    const float2 af = __half22float2(*(const __half2*)&a);
    acc = fmaf(wf.x, af.x, acc);
    return fmaf(wf.y, af.y, acc);
#endif
}

// LDS A layout: uint4 per kp; .x/.y/.z/.w = rows 0..3, each a half2 (k=2kp, 2kp+1)
__device__ __forceinline__ int hidx(int k, int r) {
    return (k >> 1) * 8 + r * 2 + (k & 1);   // half index into sAh
}

// one 4-kp chunk of one weight column-uint4 against 4 batch rows (16 dot2)
__device__ __forceinline__ void fmaC(const uint4 w, const uint4* __restrict__ A4,
                                     int kpb, float4& a) {
    const uint4 a0 = A4[kpb + 0], a1 = A4[kpb + 1], a2 = A4[kpb + 2], a3 = A4[kpb + 3];
    a.x = dot2f(w.x, a0.x, a.x); a.y = dot2f(w.x, a0.y, a.y);
    a.z = dot2f(w.x, a0.z, a.z); a.w = dot2f(w.x, a0.w, a.w);
    a.x = dot2f(w.y, a1.x, a.x); a.y = dot2f(w.y, a1.y, a.y);
    a.z = dot2f(w.y, a1.z, a.z); a.w = dot2f(w.y, a1.w, a.w);
    a.x = dot2f(w.z, a2.x, a.x); a.y = dot2f(w.z, a2.y, a.y);
    a.z = dot2f(w.z, a2.z, a.z); a.w = dot2f(w.z, a2.w, a.w);
    a.x = dot2f(w.w, a3.x, a.x); a.y = dot2f(w.w, a3.y, a.y);
    a.z = dot2f(w.w, a3.z, a.z); a.w = dot2f(w.w, a3.w, a.w);
}

// load 2 chunks (cb, cb+1; clamped to < cbMax) x up-to-4 column groups
__device__ __forceinline__ void ldG2(uint4* w, const uint4* __restrict__ M4,
                                     int ldm, int cb, int G, int cbMax) {
    #pragma unroll
    for (int u = 0; u < 2; ++u) {
        const int cc = (cb + u < cbMax) ? (cb + u) : (cbMax - 1);
        #pragma unroll
        for (int g = 0; g < 4; ++g)
            if (g < G) w[u * 4 + g] = M4[(size_t)cc * ldm + g * 256];
    }
}
// consume 2 chunks (kp base kpb0 = cb*4)
__device__ __forceinline__ void fmaG2(const uint4* w, const uint4* __restrict__ A4,
                                      int kpb0, int G, float4* acc) {
    #pragma unroll
    for (int u = 0; u < 2; ++u)
        #pragma unroll
        for (int g = 0; g < 4; ++g)
            if (g < G) fmaC(w[u * 4 + g], A4, kpb0 + u * 4, acc[g]);
}
// consume 1 chunk from the low half of a buffer
__device__ __forceinline__ void fmaG1(const uint4* w, const uint4* __restrict__ A4,
                                      int kpb0, int G, float4* acc) {
    #pragma unroll
    for (int g = 0; g < 4; ++g)
        if (g < G) fmaC(w[g], A4, kpb0, acc[g]);
}

// weight f32 -> paired fp16, chunk-tiled transposed layout (per launch)
__global__ void cvt_pair(const float* __restrict__ src, unsigned* __restrict__ dst,
                         int n, int ld) {
    const int i = blockIdx.x * 256 + threadIdx.x;
    if (i >= n) return;
    const int kp = i / ld, col = i - kp * ld;
    const __half2 h = __floats2half2_rn(src[(2 * kp) * ld + col],
                                        src[(2 * kp + 1) * ld + col]);
    dst[((size_t)((kp >> 2) * ld + col) << 2) + (kp & 3)] = *(const unsigned*)&h;
}

// roles: 0 = p0 (x->P0), 1 = r0 (U0 + h0 update), 2 = p1 (h0->P1), 3 = r1 (U1 + head)
// bx = (chain*4+role) + 8*rg
// 1024 threads/block: grp = tid>>8 (4-way K split), c = tid&255 (column).
// Each thread owns ONE batch row (rA = grp) for state/update work.
__global__ void __launch_bounds__(1024, 4)
rnn_persist(const float* __restrict__ x, const int* __restrict__ lengths,
            const float* __restrict__ gbi0, const float* __restrict__ gbr0,
            const float* __restrict__ gbi1, const float* __restrict__ gbr1,
            const float* __restrict__ lb0, const float* __restrict__ lb1,
            const float* __restrict__ outW, const float* __restrict__ outb,
            float* __restrict__ out, char* __restrict__ wsb)
{
    const int tid = threadIdx.x;
    const int c   = tid & 255;
    const int grp = tid >> 8;                // 0..3
    const int bx  = blockIdx.x;
    const int role  = bx & 3;
    const int chain = (bx >> 2) & 1;
    const int rg    = bx >> 3;
    const int rowbase = rg * 4;

    const int GA  = chain ? 4 : 3;
    const int GAH = GA * Hh;

    u64* h0ring = (u64*)wsb + (size_t)(chain * 16 + rg) * (NS0 * 1024);
    u64* p0ring = (u64*)(wsb + OFF_P0) + (size_t)(chain * 16 + rg) * (NSP * 4096);
    u64* p1ring = (u64*)(wsb + OFF_P1) + (size_t)(chain * 16 + rg) * (NSP * 4096);
    int* flags = (int*)(wsb + OFF_FLG);
    int* flg_r0 = flags + ((chain * 16 + rg) * 4 + 1) * 32;
    int* flg_p1 = flags + ((chain * 16 + rg) * 4 + 2) * 32;
    int* flg_r1 = flags + ((chain * 16 + rg) * 4 + 3) * 32;

    const unsigned* W16 = (const unsigned*)(wsb + OFF_W16);
    size_t woff;
    if (chain == 0) woff = (role == 0) ? oGW0 : (role == 1) ? oGU0 : (role == 2) ? oGW1 : oGU1;
    else            woff = (role == 0) ? oLW0 : (role == 1) ? oLU0 : (role == 2) ? oLW1 : oLU1;
    const uint4* M4 = (const uint4*)(W16 + woff) + c;

    const int KR  = (role == 0) ? Dd : Hh;
    const int KP2 = KR >> 3;                 // kp per group (12 or 32)
    const int kp0 = grp * KP2;
    const int cb0 = kp0 >> 2;                // first chunk
    const int n4  = KP2 >> 2;                // 3 or 8 chunks
    const int cbEnd = cb0 + n4;

    __shared__ __align__(16) unsigned sAh[128 * 4];   // uint4[kp]: rows' half2
    __shared__ float sG[2 * 4096];           // 2 folded partial buffers
    __shared__ float sP[4096];
    __shared__ float sRed[16];
    __half* sAhh = (__half*)sAh;
    const uint4* A4 = (const uint4*)sAh;

    const int NP  = 4 * GAH;                 // 3072 or 4096
    const int npt = NP >> 10;                // 3 or 4 per thread at 1024 threads
    float biasv[4];
    int sgidx[4];
    if (role == 0 || role == 2) {
        const float* bsrc = (chain == 0) ? (role == 0 ? gbi0 : gbi1)
                                         : (role == 0 ? lb0 : lb1);
        #pragma unroll
        for (int i = 0; i < 4; ++i) {
            if (i < npt) {
                const int e = tid + i * 1024;
                const int r = e / GAH, rem = e - r * GAH;
                biasv[i] = bsrc[rem];
                sgidx[i] = r * 1024 + rem;
            } else { biasv[i] = 0; sgidx[i] = 0; }
        }
    }
    const int rA = grp;                      // this thread's batch row
    const int lenA = lengths[rowbase + rA];
    float brz = 0, brr = 0, brh = 0, ow = 0;
    if (chain == 0 && (role == 1 || role == 3)) {
        const float* br = (role == 1) ? gbr0 : gbr1;
        brz = br[c]; brr = br[Hh + c]; brh = br[2 * Hh + c];
    }
    if (role == 3) ow = outW[chain * Hh + c];
    const float outb0 = outb[0];
    float creg = 0.0f;
    float hprev = 0.0f;                      // own h(t-1) f32 (exact masking)

    for (int i = tid; i < 512; i += 1024) sAh[i] = 0;   // h(-1)=0
    __syncthreads();

    for (int t = 0; t < Tt; ++t) {
        // ======= EARLY weight prefetch: issue before phase-1 so the load
        // latency overlaps the poll/stage phase (weights are t-invariant). =======
        uint4 wA[8], wB[8];
        ldG2(wA, M4, GAH, cb0,     GA, cbEnd);
        ldG2(wB, M4, GAH, cb0 + 2, GA, cbEnd);

        // =========== PHASE 1: acquire input / anti-clobber ===========
        if (role == 0) {
            if (t >= NSP) {
                if (tid == 0)
                    while (agldi(flg_r0) < t - NSP + 1) __builtin_amdgcn_s_sleep(1);
                __syncthreads();
            }
            if (tid < 4 * Dd) {
                const int r = tid / Dd, k = tid - r * Dd;
                const float v = x[((size_t)(rowbase + r) * Tt + t) * Dd + k];
                sAhh[hidx(k, r)] = __float2half(v);
            }
            __syncthreads();
        } else if (role == 2) {
            const u64* p0 = h0ring + (size_t)(t & (NS0 - 1)) * 1024 + rA * 256 + c;
            const unsigned want = (unsigned)(t + 1);
            u64 v0;
            do { v0 = agld(p0); } while ((unsigned)v0 != want);
            sAhh[hidx(c, rA)] = __float2half(__uint_as_float((unsigned)(v0 >> 32)));
            __syncthreads();
            if (tid == 0)
                __hip_atomic_exchange(flg_p1, t + 1, __ATOMIC_RELEASE,
                                      __HIP_MEMORY_SCOPE_AGENT);
        } else {
            // r0 / r1: poll the P slot into sP (poll BEFORE GEMM)
            const u64* slot = ((role == 1) ? p0ring : p1ring)
                              + (size_t)(t & (NSP - 1)) * 4096;
            const unsigned want = (unsigned)(t + 1);
            unsigned dm = 0;
            const unsigned full = (1u << npt) - 1u;
            while (dm != full) {
                for (int i = 0; i < npt; ++i) {
                    if (!(dm & (1u << i))) {
                        const u64 v = agld(slot + tid + i * 1024);
                        if ((unsigned)v == want) {
                            sP[tid + i * 1024] = __uint_as_float((unsigned)(v >> 32));
                            dm |= 1u << i;
                        }
                    }
                }
            }
            __syncthreads();
            if (tid == 0)
                __hip_atomic_exchange((role == 1) ? flg_r0 : flg_r1, t + 1,
                                      __ATOMIC_RELEASE, __HIP_MEMORY_SCOPE_AGENT);
        }

        // =========== PHASE 2: GEMM (fp16 dot2), ping-pong 2-chunk groups ===========
        {
            float4 acc[4] = {{0,0,0,0},{0,0,0,0},{0,0,0,0},{0,0,0,0}};
            if (n4 == 8) {
                fmaG2(wA, A4, (cb0 + 0) * 4, GA, acc);
                ldG2(wA, M4, GAH, cb0 + 4, GA, cbEnd);
                fmaG2(wB, A4, (cb0 + 2) * 4, GA, acc);
                ldG2(wB, M4, GAH, cb0 + 6, GA, cbEnd);
                fmaG2(wA, A4, (cb0 + 4) * 4, GA, acc);
                fmaG2(wB, A4, (cb0 + 6) * 4, GA, acc);
            } else {   // n4 == 3 (role 0): all chunks preloaded early
                fmaG2(wA, A4, (cb0 + 0) * 4, GA, acc);
                fmaG1(wB, A4, (cb0 + 2) * 4, GA, acc);
            }
            if (grp < 2) {
                #pragma unroll
                for (int g = 0; g < 4; ++g) {
                    if (g < GA) {
                        sG[grp * 4096 + 0 + g * 256 + c]    = acc[g].x;
                        sG[grp * 4096 + 1024 + g * 256 + c] = acc[g].y;
                        sG[grp * 4096 + 2048 + g * 256 + c] = acc[g].z;
                        sG[grp * 4096 + 3072 + g * 256 + c] = acc[g].w;
                    }
                }
            }
            __syncthreads();
            if (grp >= 2) {
                const int b = (grp - 2) * 4096;
                #pragma unroll
                for (int g = 0; g < 4; ++g) {
                    if (g < GA) {
                        sG[b + 0 + g * 256 + c]    += acc[g].x;
                        sG[b + 1024 + g * 256 + c] += acc[g].y;
                        sG[b + 2048 + g * 256 + c] += acc[g].z;
                        sG[b + 3072 + g * 256 + c] += acc[g].w;
                    }
                }
            }
        }
        __syncthreads();

        // =========== PHASE 3: publish (p) / update (r) ===========
        if (role == 0 || role == 2) {
            if (role == 2 && t >= NSP) {
                if (tid == 0)
                    while (agldi(flg_r1) < t - NSP + 1) __builtin_amdgcn_s_sleep(1);
                __syncthreads();
            }
            u64* ring = (role == 0) ? p0ring : p1ring;
            u64* slot = ring + (size_t)(t & (NSP - 1)) * 4096;
            for (int i = 0; i < npt; ++i) {
                const float v = sG[sgidx[i]] + sG[4096 + sgidx[i]] + biasv[i];
                agst(slot + tid + i * 1024,
                     ((u64)__float_as_uint(v) << 32) | (unsigned)(t + 1));
            }
        } else {
            if (role == 1 && t >= NS0) {
                if (tid == 0)
                    while (agldi(flg_p1) < t - NS0 + 1) __builtin_amdgcn_s_sleep(1);
                __syncthreads();
            }
            const int r = rA;
            const float hold = hprev;
            float hn;
            if (chain == 0) {
                const float Pz = sP[r * GAH + c];
                const float Pr = sP[r * GAH + Hh + c];
                const float Ph = sP[r * GAH + 2 * Hh + c];
                const float Qz = sG[r * 1024 + c]       + sG[4096 + r * 1024 + c];
                const float Qr = sG[r * 1024 + 256 + c] + sG[4096 + r * 1024 + 256 + c];
                const float Qh = sG[r * 1024 + 512 + c] + sG[4096 + r * 1024 + 512 + c];
                const float z  = sigf(Pz + Qz + brz);
                const float rr = sigf(Pr + Qr + brr);
                const float hh = tanhf(Ph + rr * (Qh + brh));
                hn = z * hold + (1.0f - z) * hh;
                if (t >= lenA) hn = hold;
            } else {
                const float gi = sP[r * GAH + c]          + sG[r * 1024 + c]       + sG[4096 + r * 1024 + c];
                const float gf = sP[r * GAH + Hh + c]     + sG[r * 1024 + 256 + c] + sG[4096 + r * 1024 + 256 + c];
                const float gc = sP[r * GAH + 2 * Hh + c] + sG[r * 1024 + 512 + c] + sG[4096 + r * 1024 + 512 + c];
                const float go = sP[r * GAH + 3 * Hh + c] + sG[r * 1024 + 768 + c] + sG[4096 + r * 1024 + 768 + c];
                float cn = sigf(gf) * creg + sigf(gi) * tanhf(gc);
                hn = sigf(go) * tanhf(cn);
                if (t >= lenA) { hn = hold; cn = creg; }
                creg = cn;
            }
            hprev = hn;
            sAhh[hidx(c, r)] = __float2half(hn);     // own h(t) for next GEMM
            if (role == 1) {
                agst(h0ring + (size_t)(t & (NS0 - 1)) * 1024 + r * 256 + c,
                     ((u64)__float_as_uint(hn) << 32) | (unsigned)(t + 1));
            } else {
                float vh = hn * ow;
                for (int o = 32; o > 0; o >>= 1)
                    vh += __shfl_down(vh, o);
                if ((tid & 63) == 0) sRed[tid >> 6] = vh;   // 16 waves
                __syncthreads();
                if (tid < 4) {
                    const float s = sRed[tid * 4] + sRed[tid * 4 + 1]
                                  + sRed[tid * 4 + 2] + sRed[tid * 4 + 3];
                    atomicAdd(&out[(size_t)(rowbase + tid) * Tt + t],
                              s + (chain ? outb0 : 0.0f));
                }
            }
        }
        __syncthreads();   // sAh/sG/sP/sRed safe for next iteration
    }
}

extern "C" void kernel_launch(void* const* d_in, const int* in_sizes, int n_in,
                              void* d_out, int out_size, void* d_ws, size_t ws_size,
                              hipStream_t stream) {
    const float* x       = (const float*)d_in[0];
    const int*   lengths = (const int*)d_in[1];
    const float* gW0  = (const float*)d_in[2];
    const float* gU0  = (const float*)d_in[3];
    const float* gbi0 = (const float*)d_in[4];
    const float* gbr0 = (const float*)d_in[5];
    const float* gW1  = (const float*)d_in[6];
    const float* gU1  = (const float*)d_in[7];
    const float* gbi1 = (const float*)d_in[8];
    const float* gbr1 = (const float*)d_in[9];
    const float* lW0  = (const float*)d_in[10];
    const float* lU0  = (const float*)d_in[11];
    const float* lb0  = (const float*)d_in[12];
    const float* lW1  = (const float*)d_in[13];
    const float* lU1  = (const float*)d_in[14];
    const float* lb1  = (const float*)d_in[15];
    const float* outW = (const float*)d_in[16];
    const float* outb = (const float*)d_in[17];
    float* out = (float*)d_out;
    char* wsb  = (char*)d_ws;

    hipMemsetAsync(d_ws, 0, OFF_FLG + (16 << 10), stream);
    hipMemsetAsync(d_out, 0, (size_t)out_size * sizeof(float), stream);

    unsigned* W16 = (unsigned*)(wsb + OFF_W16);
    struct { const float* s; size_t o; int K; int ld; } cv[8] = {
        {gW0, oGW0, 96, 768}, {gU0, oGU0, 256, 768},
        {gW1, oGW1, 256, 768}, {gU1, oGU1, 256, 768},
        {lW0, oLW0, 96, 1024}, {lU0, oLU0, 256, 1024},
        {lW1, oLW1, 256, 1024}, {lU1, oLU1, 256, 1024},
    };
    for (int i = 0; i < 8; ++i) {
        const int n = (cv[i].K / 2) * cv[i].ld;
        cvt_pair<<<(n + 255) / 256, 256, 0, stream>>>(cv[i].s, W16 + cv[i].o, n, cv[i].ld);
    }

    rnn_persist<<<dim3(128), dim3(1024), 0, stream>>>(
        x, lengths, gbi0, gbr0, gbi1, gbr1, lb0, lb1, outW, outb, out, wsb);
}

// Round 6
// 4890.421 us; speedup vs baseline: 6.7303x; 6.7303x over previous
//
#include <hip/hip_runtime.h>
#include <hip/hip_fp16.h>

// B=64, T=512, D=96, H=256
constexpr int Tt = 512, Dd = 96, Hh = 256;
constexpr int NS0 = 16;   // h0 ring depth
constexpr int NSP = 8;    // P ring depth
typedef unsigned long long u64;

// ws byte offsets:
constexpr size_t OFF_P0  = (size_t)4 << 20;
constexpr size_t OFF_P1  = (size_t)12 << 20;
constexpr size_t OFF_FLG = (size_t)20 << 20;
constexpr size_t OFF_W16 = ((size_t)20 << 20) + ((size_t)64 << 10);
constexpr size_t oGW0 = 0;
constexpr size_t oGU0 = oGW0 + (size_t)48 * 768;
constexpr size_t oGW1 = oGU0 + (size_t)128 * 768;
constexpr size_t oGU1 = oGW1 + (size_t)128 * 768;
constexpr size_t oLW0 = oGU1 + (size_t)128 * 768;
constexpr size_t oLU0 = oLW0 + (size_t)48 * 1024;
constexpr size_t oLW1 = oLU0 + (size_t)128 * 1024;
constexpr size_t oLU1 = oLW1 + (size_t)128 * 1024;

__device__ __forceinline__ float sigf(float v) { return 1.0f / (1.0f + __expf(-v)); }
__device__ __forceinline__ u64 agld(const u64* p) {
    return __hip_atomic_load(p, __ATOMIC_RELAXED, __HIP_MEMORY_SCOPE_AGENT);
}
__device__ __forceinline__ int agldi(const int* p) {
    return __hip_atomic_load(p, __ATOMIC_ACQUIRE, __HIP_MEMORY_SCOPE_AGENT);
}
// tag+payload in ONE aligned 64-bit word -> relaxed agent-scope store is a
// sufficient (single-copy atomic) publish and it coalesces.
__device__ __forceinline__ void agst(u64* p, u64 v) {
    __hip_atomic_store(p, v, __ATOMIC_RELAXED, __HIP_MEMORY_SCOPE_AGENT);
}

// fp16x2 dot into f32 accumulator (v_dot2_f32_f16)
__device__ __forceinline__ float dot2f(unsigned w, unsigned a, float acc) {
#if __has_builtin(__builtin_amdgcn_fdot2)
    typedef _Float16 h2v __attribute__((ext_vector_type(2)));
    h2v wh, ah;
    __builtin_memcpy(&wh, &w, 4);
    __builtin_memcpy(&ah, &a, 4);
    return __builtin_amdgcn_fdot2(wh, ah, acc, false);
#else
    const float2 wf = __half22float2(*(const __half2*)&w);
    const float2 af = __half22float2(*(const __half2*)&a);
    acc = fmaf(wf.x, af.x, acc);
    return fmaf(wf.y, af.y, acc);
#endif
}

// LDS A layout: uint4 per kp; .x/.y/.z/.w = rows 0..3, each a half2 (k=2kp, 2kp+1)
__device__ __forceinline__ int hidx(int k, int r) {
    return (k >> 1) * 8 + r * 2 + (k & 1);   // half index into sAh
}

// ---- fp16-pair GEMM, 4-kp chunks, depth-2 pipeline (R3-identical, no spill) ----
template<int G>
__device__ __forceinline__ void load4h(uint4* wv, const uint4* __restrict__ M4,
                                       int ldm, int kpb) {
    const int base = (kpb >> 2) * ldm;
    #pragma unroll
    for (int g = 0; g < G; ++g)
        wv[g] = M4[base + g * 256];
}
template<int G>
__device__ __forceinline__ void fma4h(const uint4* wv, const uint4* __restrict__ A4,
                                      int kpb, float4* acc) {
    const uint4 a0 = A4[kpb + 0];
    const uint4 a1 = A4[kpb + 1];
    const uint4 a2 = A4[kpb + 2];
    const uint4 a3 = A4[kpb + 3];
    #pragma unroll
    for (int g = 0; g < G; ++g) {
        const uint4 w = wv[g];
        acc[g].x = dot2f(w.x, a0.x, acc[g].x);
        acc[g].y = dot2f(w.x, a0.y, acc[g].y);
        acc[g].z = dot2f(w.x, a0.z, acc[g].z);
        acc[g].w = dot2f(w.x, a0.w, acc[g].w);
        acc[g].x = dot2f(w.y, a1.x, acc[g].x);
        acc[g].y = dot2f(w.y, a1.y, acc[g].y);
        acc[g].z = dot2f(w.y, a1.z, acc[g].z);
        acc[g].w = dot2f(w.y, a1.w, acc[g].w);
        acc[g].x = dot2f(w.z, a2.x, acc[g].x);
        acc[g].y = dot2f(w.z, a2.y, acc[g].y);
        acc[g].z = dot2f(w.z, a2.z, acc[g].z);
        acc[g].w = dot2f(w.z, a2.w, acc[g].w);
        acc[g].x = dot2f(w.w, a3.x, acc[g].x);
        acc[g].y = dot2f(w.w, a3.y, acc[g].y);
        acc[g].z = dot2f(w.w, a3.z, acc[g].z);
        acc[g].w = dot2f(w.w, a3.w, acc[g].w);
    }
}
template<int G>
__device__ __forceinline__ void gemmP(const uint4* __restrict__ M4, int ldm,
                                      const uint4* __restrict__ A4,
                                      int kp0, int kp1, float4* acc) {
    const int n4 = (kp1 - kp0) >> 2;
    uint4 wv0[G], wv1[G];
    if (n4 <= 0) return;
    load4h<G>(wv0, M4, ldm, kp0);
    int c2 = 0;
    for (; c2 + 2 <= n4; c2 += 2) {
        load4h<G>(wv1, M4, ldm, kp0 + (c2 + 1) * 4);
        fma4h<G>(wv0, A4, kp0 + c2 * 4, acc);
        if (c2 + 2 < n4) load4h<G>(wv0, M4, ldm, kp0 + (c2 + 2) * 4);
        fma4h<G>(wv1, A4, kp0 + (c2 + 1) * 4, acc);
    }
    if (c2 < n4) fma4h<G>(wv0, A4, kp0 + c2 * 4, acc);
}

// weight f32 -> paired fp16, chunk-tiled transposed layout (per launch)
__global__ void cvt_pair(const float* __restrict__ src, unsigned* __restrict__ dst,
                         int n, int ld) {
    const int i = blockIdx.x * 256 + threadIdx.x;
    if (i >= n) return;
    const int kp = i / ld, col = i - kp * ld;
    const __half2 h = __floats2half2_rn(src[(2 * kp) * ld + col],
                                        src[(2 * kp + 1) * ld + col]);
    dst[((size_t)((kp >> 2) * ld + col) << 2) + (kp & 3)] = *(const unsigned*)&h;
}

// roles: 0 = p0 (x->P0), 1 = r0 (U0 + h0 update), 2 = p1 (h0->P1), 3 = r1 (U1 + head)
// bx = (chain*4+role) + 8*rg
// 1024 threads/block: grp = tid>>8 (4-way K split), c = tid&255 (column).
// Each thread owns ONE batch row (rA = grp) for state/update work.
// R6 change: r-roles run GEMM FIRST, then poll their P values DIRECTLY into
// registers (each thread polls exactly the GA gate values for its (row,unit)).
// Removes the publish->poll wait from before the independent GEMM, kills sP
// and one barrier.
__global__ void __launch_bounds__(1024, 4)
rnn_persist(const float* __restrict__ x, const int* __restrict__ lengths,
            const float* __restrict__ gbi0, const float* __restrict__ gbr0,
            const float* __restrict__ gbi1, const float* __restrict__ gbr1,
            const float* __restrict__ lb0, const float* __restrict__ lb1,
            const float* __restrict__ outW, const float* __restrict__ outb,
            float* __restrict__ out, char* __restrict__ wsb)
{
    const int tid = threadIdx.x;
    const int c   = tid & 255;
    const int grp = tid >> 8;                // 0..3
    const int bx  = blockIdx.x;
    const int role  = bx & 3;
    const int chain = (bx >> 2) & 1;
    const int rg    = bx >> 3;
    const int rowbase = rg * 4;

    const int GA  = chain ? 4 : 3;
    const int GAH = GA * Hh;

    u64* h0ring = (u64*)wsb + (size_t)(chain * 16 + rg) * (NS0 * 1024);
    u64* p0ring = (u64*)(wsb + OFF_P0) + (size_t)(chain * 16 + rg) * (NSP * 4096);
    u64* p1ring = (u64*)(wsb + OFF_P1) + (size_t)(chain * 16 + rg) * (NSP * 4096);
    int* flags = (int*)(wsb + OFF_FLG);
    int* flg_r0 = flags + ((chain * 16 + rg) * 4 + 1) * 32;
    int* flg_p1 = flags + ((chain * 16 + rg) * 4 + 2) * 32;
    int* flg_r1 = flags + ((chain * 16 + rg) * 4 + 3) * 32;

    const unsigned* W16 = (const unsigned*)(wsb + OFF_W16);
    size_t woff;
    if (chain == 0) woff = (role == 0) ? oGW0 : (role == 1) ? oGU0 : (role == 2) ? oGW1 : oGU1;
    else            woff = (role == 0) ? oLW0 : (role == 1) ? oLU0 : (role == 2) ? oLW1 : oLU1;
    const uint4* M4 = (const uint4*)(W16 + woff) + c;

    const int KR  = (role == 0) ? Dd : Hh;
    const int KP2 = KR >> 3;                 // kp per group (12 or 32)
    const int kp0 = grp * KP2, kp1 = kp0 + KP2;

    __shared__ __align__(16) unsigned sAh[128 * 4];   // uint4[kp]: rows' half2
    __shared__ float sG[2 * 4096];           // 2 folded partial buffers
    __shared__ float sRed[16];
    __half* sAhh = (__half*)sAh;
    const uint4* A4 = (const uint4*)sAh;

    const int NP  = 4 * GAH;                 // 3072 or 4096
    const int npt = NP >> 10;                // 3 or 4 per thread at 1024 threads
    float biasv[4];
    int sgidx[4];
    if (role == 0 || role == 2) {
        const float* bsrc = (chain == 0) ? (role == 0 ? gbi0 : gbi1)
                                         : (role == 0 ? lb0 : lb1);
        #pragma unroll
        for (int i = 0; i < 4; ++i) {
            if (i < npt) {
                const int e = tid + i * 1024;
                const int r = e / GAH, rem = e - r * GAH;
                biasv[i] = bsrc[rem];
                sgidx[i] = r * 1024 + rem;
            } else { biasv[i] = 0; sgidx[i] = 0; }
        }
    }
    const int rA = grp;                      // this thread's batch row
    const int lenA = lengths[rowbase + rA];
    float brz = 0, brr = 0, brh = 0, ow = 0;
    if (chain == 0 && (role == 1 || role == 3)) {
        const float* br = (role == 1) ? gbr0 : gbr1;
        brz = br[c]; brr = br[Hh + c]; brh = br[2 * Hh + c];
    }
    if (role == 3) ow = outW[chain * Hh + c];
    const float outb0 = outb[0];
    float creg = 0.0f;
    float hprev = 0.0f;                      // own h(t-1) f32 (exact masking)

    for (int i = tid; i < 512; i += 1024) sAh[i] = 0;   // h(-1)=0
    __syncthreads();

    for (int t = 0; t < Tt; ++t) {
        // =========== PHASE 1: acquire input (p-roles only) ===========
        if (role == 0) {
            if (t >= NSP) {
                if (tid == 0)
                    while (agldi(flg_r0) < t - NSP + 1) __builtin_amdgcn_s_sleep(1);
                __syncthreads();
            }
            if (tid < 4 * Dd) {
                const int r = tid / Dd, k = tid - r * Dd;
                const float v = x[((size_t)(rowbase + r) * Tt + t) * Dd + k];
                sAhh[hidx(k, r)] = __float2half(v);
            }
            __syncthreads();
        } else if (role == 2) {
            const u64* p0 = h0ring + (size_t)(t & (NS0 - 1)) * 1024 + rA * 256 + c;
            const unsigned want = (unsigned)(t + 1);
            u64 v0;
            do { v0 = agld(p0); } while ((unsigned)v0 != want);
            sAhh[hidx(c, rA)] = __float2half(__uint_as_float((unsigned)(v0 >> 32)));
            __syncthreads();
            if (tid == 0)
                __hip_atomic_exchange(flg_p1, t + 1, __ATOMIC_RELEASE,
                                      __HIP_MEMORY_SCOPE_AGENT);
        }
        // r-roles: no phase 1 — sAh holds h(t-1) from the previous step.

        // =========== PHASE 2: GEMM (fp16 dot2), 4-way K split + fold ===========
        if (chain == 0) {
            float4 acc[3] = {{0,0,0,0},{0,0,0,0},{0,0,0,0}};
            gemmP<3>(M4, GAH, A4, kp0, kp1, acc);
            if (grp < 2) {
                #pragma unroll
                for (int g = 0; g < 3; ++g) {
                    sG[grp * 4096 + 0 + g * 256 + c]    = acc[g].x;
                    sG[grp * 4096 + 1024 + g * 256 + c] = acc[g].y;
                    sG[grp * 4096 + 2048 + g * 256 + c] = acc[g].z;
                    sG[grp * 4096 + 3072 + g * 256 + c] = acc[g].w;
                }
            }
            __syncthreads();
            if (grp >= 2) {
                const int b = (grp - 2) * 4096;
                #pragma unroll
                for (int g = 0; g < 3; ++g) {
                    sG[b + 0 + g * 256 + c]    += acc[g].x;
                    sG[b + 1024 + g * 256 + c] += acc[g].y;
                    sG[b + 2048 + g * 256 + c] += acc[g].z;
                    sG[b + 3072 + g * 256 + c] += acc[g].w;
                }
            }
        } else {
            float4 acc[4] = {{0,0,0,0},{0,0,0,0},{0,0,0,0},{0,0,0,0}};
            gemmP<4>(M4, GAH, A4, kp0, kp1, acc);
            if (grp < 2) {
                #pragma unroll
                for (int g = 0; g < 4; ++g) {
                    sG[grp * 4096 + 0 + g * 256 + c]    = acc[g].x;
                    sG[grp * 4096 + 1024 + g * 256 + c] = acc[g].y;
                    sG[grp * 4096 + 2048 + g * 256 + c] = acc[g].z;
                    sG[grp * 4096 + 3072 + g * 256 + c] = acc[g].w;
                }
            }
            __syncthreads();
            if (grp >= 2) {
                const int b = (grp - 2) * 4096;
                #pragma unroll
                for (int g = 0; g < 4; ++g) {
                    sG[b + 0 + g * 256 + c]    += acc[g].x;
                    sG[b + 1024 + g * 256 + c] += acc[g].y;
                    sG[b + 2048 + g * 256 + c] += acc[g].z;
                    sG[b + 3072 + g * 256 + c] += acc[g].w;
                }
            }
        }
        __syncthreads();

        // =========== PHASE 3: publish (p) / poll+update (r) ===========
        if (role == 0 || role == 2) {
            if (role == 2 && t >= NSP) {
                if (tid == 0)
                    while (agldi(flg_r1) < t - NSP + 1) __builtin_amdgcn_s_sleep(1);
                __syncthreads();
            }
            u64* ring = (role == 0) ? p0ring : p1ring;
            u64* slot = ring + (size_t)(t & (NSP - 1)) * 4096;
            for (int i = 0; i < npt; ++i) {
                const float v = sG[sgidx[i]] + sG[4096 + sgidx[i]] + biasv[i];
                agst(slot + tid + i * 1024,
                     ((u64)__float_as_uint(v) << 32) | (unsigned)(t + 1));
            }
        } else {
            // direct-register poll: exactly the GA gate values this thread needs
            const u64* slot = ((role == 1) ? p0ring : p1ring)
                              + (size_t)(t & (NSP - 1)) * 4096 + rA * GAH + c;
            const unsigned want = (unsigned)(t + 1);
            float P_[4] = {0, 0, 0, 0};
            unsigned dm = 0;
            const unsigned full = (1u << GA) - 1u;
            while (dm != full) {
                #pragma unroll
                for (int g = 0; g < 4; ++g) {
                    if (g < GA && !(dm & (1u << g))) {
                        const u64 v = agld(slot + g * 256);
                        if ((unsigned)v == want) {
                            P_[g] = __uint_as_float((unsigned)(v >> 32));
                            dm |= 1u << g;
                        }
                    }
                }
            }
            if (role == 1 && t >= NS0) {
                if (tid == 0)
                    while (agldi(flg_p1) < t - NS0 + 1) __builtin_amdgcn_s_sleep(1);
                __syncthreads();
            }
            const int r = rA;
            const float hold = hprev;
            float hn;
            if (chain == 0) {
                const float Qz = sG[r * 1024 + c]       + sG[4096 + r * 1024 + c];
                const float Qr = sG[r * 1024 + 256 + c] + sG[4096 + r * 1024 + 256 + c];
                const float Qh = sG[r * 1024 + 512 + c] + sG[4096 + r * 1024 + 512 + c];
                const float z  = sigf(P_[0] + Qz + brz);
                const float rr = sigf(P_[1] + Qr + brr);
                const float hh = tanhf(P_[2] + rr * (Qh + brh));
                hn = z * hold + (1.0f - z) * hh;
                if (t >= lenA) hn = hold;
            } else {
                const float gi = P_[0] + sG[r * 1024 + c]       + sG[4096 + r * 1024 + c];
                const float gf = P_[1] + sG[r * 1024 + 256 + c] + sG[4096 + r * 1024 + 256 + c];
                const float gc = P_[2] + sG[r * 1024 + 512 + c] + sG[4096 + r * 1024 + 512 + c];
                const float go = P_[3] + sG[r * 1024 + 768 + c] + sG[4096 + r * 1024 + 768 + c];
                float cn = sigf(gf) * creg + sigf(gi) * tanhf(gc);
                hn = sigf(go) * tanhf(cn);
                if (t >= lenA) { hn = hold; cn = creg; }
                creg = cn;
            }
            hprev = hn;
            sAhh[hidx(c, r)] = __float2half(hn);     // own h(t) for next GEMM
            if (role == 1) {
                agst(h0ring + (size_t)(t & (NS0 - 1)) * 1024 + r * 256 + c,
                     ((u64)__float_as_uint(hn) << 32) | (unsigned)(t + 1));
            } else {
                float vh = hn * ow;
                for (int o = 32; o > 0; o >>= 1)
                    vh += __shfl_down(vh, o);
                if ((tid & 63) == 0) sRed[tid >> 6] = vh;   // 16 waves
                __syncthreads();
                if (tid < 4) {
                    const float s = sRed[tid * 4] + sRed[tid * 4 + 1]
                                  + sRed[tid * 4 + 2] + sRed[tid * 4 + 3];
                    atomicAdd(&out[(size_t)(rowbase + tid) * Tt + t],
                              s + (chain ? outb0 : 0.0f));
                }
            }
        }
        __syncthreads();   // sAh/sG/sRed safe for next iteration; polls all done
        if (tid == 0 && (role == 1 || role == 3)) {
            // release: P slot t consumed (after barrier => all threads polled)
            __hip_atomic_exchange((role == 1) ? flg_r0 : flg_r1, t + 1,
                                  __ATOMIC_RELEASE, __HIP_MEMORY_SCOPE_AGENT);
        }
    }
}

extern "C" void kernel_launch(void* const* d_in, const int* in_sizes, int n_in,
                              void* d_out, int out_size, void* d_ws, size_t ws_size,
                              hipStream_t stream) {
    const float* x       = (const float*)d_in[0];
    const int*   lengths = (const int*)d_in[1];
    const float* gW0  = (const float*)d_in[2];
    const float* gU0  = (const float*)d_in[3];
    const float* gbi0 = (const float*)d_in[4];
    const float* gbr0 = (const float*)d_in[5];
    const float* gW1  = (const float*)d_in[6];
    const float* gU1  = (const float*)d_in[7];
    const float* gbi1 = (const float*)d_in[8];
    const float* gbr1 = (const float*)d_in[9];
    const float* lW0  = (const float*)d_in[10];
    const float* lU0  = (const float*)d_in[11];
    const float* lb0  = (const float*)d_in[12];
    const float* lW1  = (const float*)d_in[13];
    const float* lU1  = (const float*)d_in[14];
    const float* lb1  = (const float*)d_in[15];
    const float* outW = (const float*)d_in[16];
    const float* outb = (const float*)d_in[17];
    float* out = (float*)d_out;
    char* wsb  = (char*)d_ws;

    hipMemsetAsync(d_ws, 0, OFF_FLG + (16 << 10), stream);
    hipMemsetAsync(d_out, 0, (size_t)out_size * sizeof(float), stream);

    unsigned* W16 = (unsigned*)(wsb + OFF_W16);
    struct { const float* s; size_t o; int K; int ld; } cv[8] = {
        {gW0, oGW0, 96, 768}, {gU0, oGU0, 256, 768},
        {gW1, oGW1, 256, 768}, {gU1, oGU1, 256, 768},
        {lW0, oLW0, 96, 1024}, {lU0, oLU0, 256, 1024},
        {lW1, oLW1, 256, 1024}, {lU1, oLU1, 256, 1024},
    };
    for (int i = 0; i < 8; ++i) {
        const int n = (cv[i].K / 2) * cv[i].ld;
        cvt_pair<<<(n + 255) / 256, 256, 0, stream>>>(cv[i].s, W16 + cv[i].o, n, cv[i].ld);
    }

    rnn_persist<<<dim3(128), dim3(1024), 0, stream>>>(
        x, lengths, gbi0, gbr0, gbi1, gbr1, lb0, lb1, outW, outb, out, wsb);
}